// Round 3
// baseline (600.339 us; speedup 1.0000x reference)
//
#include <hip/hip_runtime.h>
#include <hip/hip_fp16.h>
#include <stdint.h>

#define NEG_ (-1e9f)

typedef _Float16 f16x8 __attribute__((ext_vector_type(8)));
typedef float    f32x4 __attribute__((ext_vector_type(4)));

__device__ __forceinline__ float fast_tanh(float x) {
  float e = __expf(2.0f * x);
  return (e - 1.0f) * __builtin_amdgcn_rcpf(e + 1.0f);
}

// ---------------------------------------------------------------------------
// K0: repack W [512 o][512 h] fp32 -> f16 in MFMA A-fragment stream order.
// seg = oc*256 + w*64 + ks*4 + io  (1KB each);
// lane i holds W[o = oc*256+w*64+io*16+(i&15)][k = ks*32+(i>>4)*8 .. +8)
// ---------------------------------------------------------------------------
__global__ __launch_bounds__(256) void k0_cvt_w(const float* __restrict__ W,
                                                __half* __restrict__ Wws) {
  int g = blockIdx.x * 256 + threadIdx.x;   // 0..32767, one 16B chunk each
  int lane = g & 63;
  int seg  = g >> 6;                        // 0..511
  int io = seg & 3, ks = (seg >> 2) & 15, w = (seg >> 6) & 3, oc = seg >> 8;
  int o = oc * 256 + w * 64 + io * 16 + (lane & 15);
  int k = ks * 32 + (lane >> 4) * 8;
  const float2* src = (const float2*)(W + (size_t)o * 512 + k);
  __half2 h[4];
#pragma unroll
  for (int j = 0; j < 4; ++j) { float2 f = src[j]; h[j] = __floats2half2_rn(f.x, f.y); }
  uint4 u;
  u.x = *(uint32_t*)&h[0]; u.y = *(uint32_t*)&h[1];
  u.z = *(uint32_t*)&h[2]; u.w = *(uint32_t*)&h[3];
  *(uint4*)(Wws + (size_t)seg * 512 + (size_t)lane * 8) = u;
}

// ---------------------------------------------------------------------------
// K1: scores[m] = mask[m] ? v . tanh(W x_m + b) : -1e9 for 64 rows per block.
// X tile staged once to LDS (swizzled f16). 4 waves x (64o x 64s), oc loop x2
// (runtime index -> small code, but ALL register-array indices are static).
// A operand from L2 with static ping-pong double-buffer (aP/aQ).
// ---------------------------------------------------------------------------
__global__ __launch_bounds__(256, 2) void k1_scores(
    const float* __restrict__ enc, const int* __restrict__ msk,
    const float* __restrict__ bias, const float* __restrict__ ctx,
    const __half* __restrict__ Wws, float* __restrict__ scores) {
  __shared__ __align__(16) __half Xl[64 * 512];  // 64 KB -> 2 blocks/CU

  const int t = threadIdx.x;
  const int w = t >> 6;
  const int lane = t & 63;
  const int quad = lane >> 4;
  const int l15 = lane & 15;
  const size_t mtile = blockIdx.x;

  const __half* wbase = Wws + (size_t)lane * 8;  // + seg*512 halves per fragment

  // Preload A for iter 0 FIRST: its L2 latency hides under the staging loads.
  f16x8 aP[4], aQ[4];
#pragma unroll
  for (int io = 0; io < 4; ++io)
    aP[io] = *(const f16x8*)(wbase + (size_t)(w * 64 + io) * 512);

  // ---- stage X tile [64 s][512 h] fp32 -> f16, XOR-swizzled 16B chunks ----
  {
    const float4* Xg = (const float4*)(enc + mtile * (size_t)(64 * 512));
#pragma unroll 8
    for (int j = 0; j < 16; ++j) {
      int g = j * 256 + t;        // f16 16B-chunk index 0..4095
      int s = g >> 6, c = g & 63;
      float4 x0 = Xg[s * 128 + 2 * c];
      float4 x1 = Xg[s * 128 + 2 * c + 1];
      __half2 h0 = __floats2half2_rn(x0.x, x0.y);
      __half2 h1 = __floats2half2_rn(x0.z, x0.w);
      __half2 h2 = __floats2half2_rn(x1.x, x1.y);
      __half2 h3 = __floats2half2_rn(x1.z, x1.w);
      uint4 u;
      u.x = *(uint32_t*)&h0; u.y = *(uint32_t*)&h1;
      u.z = *(uint32_t*)&h2; u.w = *(uint32_t*)&h3;
      int pc = c ^ (s & 7);     // bijective per wave -> conflict-free writes
      *(uint4*)&Xl[s * 512 + pc * 8] = u;
    }
  }
  __syncthreads();

  float sacc[4] = {0.f, 0.f, 0.f, 0.f};

  for (int oc = 0; oc < 2; ++oc) {   // runtime oc: feeds addresses only
    f32x4 acc[4][4];
#pragma unroll
    for (int io = 0; io < 4; ++io)
#pragma unroll
      for (int is = 0; is < 4; ++is) acc[io][is] = (f32x4){0.f, 0.f, 0.f, 0.f};

    const int segbase = oc * 256 + w * 64;

#pragma unroll
    for (int kk = 0; kk < 16; kk += 2) {
      // ---- even sub-iter: consume aP, prefetch kk+1 into aQ ----
      {
        const __half* np = wbase + (size_t)(segbase + (kk + 1) * 4) * 512;
#pragma unroll
        for (int io = 0; io < 4; ++io) aQ[io] = *(const f16x8*)(np + (size_t)io * 512);
#pragma unroll
        for (int is = 0; is < 4; ++is) {
          int s = is * 16 + l15;
          const f16x8 bf = *(const f16x8*)&Xl[s * 512 + (((kk * 4 + quad) ^ (s & 7)) << 3)];
#pragma unroll
          for (int io = 0; io < 4; ++io)
            acc[io][is] = __builtin_amdgcn_mfma_f32_16x16x32_f16(aP[io], bf, acc[io][is], 0, 0, 0);
        }
      }
      // ---- odd sub-iter: consume aQ, prefetch kk+2 (may cross oc) into aP ----
      {
        int niter = oc * 16 + kk + 2;                 // 2..32
        int nseg = (niter < 32) ? ((niter >> 4) * 256 + w * 64 + (niter & 15) * 4) : 0;
        const __half* np = wbase + (size_t)nseg * 512;  // dummy seg 0 on last iter
#pragma unroll
        for (int io = 0; io < 4; ++io) aP[io] = *(const f16x8*)(np + (size_t)io * 512);
#pragma unroll
        for (int is = 0; is < 4; ++is) {
          int s = is * 16 + l15;
          const f16x8 bf = *(const f16x8*)&Xl[s * 512 + ((((kk + 1) * 4 + quad) ^ (s & 7)) << 3)];
#pragma unroll
          for (int io = 0; io < 4; ++io)
            acc[io][is] = __builtin_amdgcn_mfma_f32_16x16x32_f16(aQ[io], bf, acc[io][is], 0, 0, 0);
        }
      }
    }

    // epilogue: fold tanh(acc + b) * v into per-row partial scores
    float ps[4] = {0.f, 0.f, 0.f, 0.f};
#pragma unroll
    for (int io = 0; io < 4; ++io) {
      int ob = oc * 256 + w * 64 + io * 16 + quad * 4;  // C row m = quad*4 + reg
      float4 b4 = *(const float4*)(bias + ob);
      float4 v4 = *(const float4*)(ctx + ob);
#pragma unroll
      for (int is = 0; is < 4; ++is) {
        const f32x4 a = acc[io][is];
        ps[is] += fast_tanh(a[0] + b4.x) * v4.x + fast_tanh(a[1] + b4.y) * v4.y +
                  fast_tanh(a[2] + b4.z) * v4.z + fast_tanh(a[3] + b4.w) * v4.w;
      }
    }
#pragma unroll
    for (int is = 0; is < 4; ++is) {   // sum over this wave's 64 o's
      float p = ps[is];
      p += __shfl_xor(p, 16, 64);
      p += __shfl_xor(p, 32, 64);
      sacc[is] += p;
    }
  }

  // cross-wave reduction (X tile dead -> reuse its LDS)
  __syncthreads();
  float* sred = (float*)&Xl[0];
  if (lane < 16) {
#pragma unroll
    for (int is = 0; is < 4; ++is) sred[w * 64 + is * 16 + lane] = sacc[is];
  }
  __syncthreads();
  if (t < 64) {
    float sc = sred[t] + sred[64 + t] + sred[128 + t] + sred[192 + t];
    size_t row = mtile * 64 + t;
    scores[row] = msk[row] ? sc : NEG_;
  }
}

// ---------------------------------------------------------------------------
// K2: in-place masked softmax over S=2048 per batch row (scores -> attn)
// ---------------------------------------------------------------------------
__global__ __launch_bounds__(256) void k2_softmax(float* __restrict__ attn) {
  const int b = blockIdx.x, t = threadIdx.x;
  float* row = attn + (size_t)b * 2048;
  float v[8];
  float mx = -3.4e38f;
#pragma unroll
  for (int i = 0; i < 8; ++i) { v[i] = row[t + 256 * i]; mx = fmaxf(mx, v[i]); }
#pragma unroll
  for (int off = 32; off >= 1; off >>= 1) mx = fmaxf(mx, __shfl_xor(mx, off, 64));
  __shared__ float r1[4], r2[4];
  int w = t >> 6, lane = t & 63;
  if (lane == 0) r1[w] = mx;
  __syncthreads();
  mx = fmaxf(fmaxf(r1[0], r1[1]), fmaxf(r1[2], r1[3]));
  float sum = 0.f;
#pragma unroll
  for (int i = 0; i < 8; ++i) { v[i] = __expf(v[i] - mx); sum += v[i]; }
#pragma unroll
  for (int off = 32; off >= 1; off >>= 1) sum += __shfl_xor(sum, off, 64);
  if (lane == 0) r2[w] = sum;
  __syncthreads();
  sum = r2[0] + r2[1] + r2[2] + r2[3];
  float inv = 1.0f / sum;
#pragma unroll
  for (int i = 0; i < 8; ++i) row[t + 256 * i] = v[i] * inv;
}

// ---------------------------------------------------------------------------
// K3a: partial[b,sc,h] = sum_{s in chunk sc} attn[b,s] * x[b,s,h]
// 2048 blocks (64 b x 32 chunks of 64 rows). NO atomics: coalesced partial
// stores. Each thread owns one float2 column across all 64 rows.
// ---------------------------------------------------------------------------
__global__ __launch_bounds__(256) void k3a_wsum(const float* __restrict__ enc,
                                                const float* __restrict__ attn,
                                                float* __restrict__ part) {
  const int bb = blockIdx.x >> 5, sc = blockIdx.x & 31, t = threadIdx.x;
  __shared__ float a_s[64];
  if (t < 64) a_s[t] = attn[(size_t)bb * 2048 + sc * 64 + t];
  __syncthreads();
  const float2* Xg = (const float2*)(enc + ((size_t)bb * 2048 + (size_t)sc * 64) * 512) + t;
  float2 acc = {0.f, 0.f};
#pragma unroll 8
  for (int s = 0; s < 64; ++s) {
    float a = a_s[s];
    float2 x = Xg[(size_t)s * 256];
    acc.x = fmaf(a, x.x, acc.x);
    acc.y = fmaf(a, x.y, acc.y);
  }
  *(float2*)(part + ((size_t)blockIdx.x * 512) + 2 * t) = acc;
}

// ---------------------------------------------------------------------------
// K3b: out[b,h] = sum_{sc<32} part[b,sc,h]
// ---------------------------------------------------------------------------
__global__ __launch_bounds__(256) void k3b_reduce(const float* __restrict__ part,
                                                  float* __restrict__ out0) {
  const int idx = blockIdx.x * 256 + threadIdx.x;  // 0..32767
  const int b = idx >> 9, h = idx & 511;
  const float* p = part + (size_t)b * 32 * 512 + h;
  float s = 0.f;
#pragma unroll
  for (int sc = 0; sc < 32; ++sc) s += p[(size_t)sc * 512];
  out0[idx] = s;
}

// ---------------------------------------------------------------------------
extern "C" void kernel_launch(void* const* d_in, const int* in_sizes, int n_in,
                              void* d_out, int out_size, void* d_ws, size_t ws_size,
                              hipStream_t stream) {
  (void)in_sizes; (void)n_in; (void)out_size; (void)ws_size;
  const float* enc  = (const float*)d_in[0];  // [64,2048,512] fp32
  const int*   msk  = (const int*)d_in[1];    // [64,2048] bool->int32
  const float* W    = (const float*)d_in[2];  // [512,512] fp32
  const float* bias = (const float*)d_in[3];  // [512] fp32
  const float* ctx  = (const float*)d_in[4];  // [512] fp32
  float* out0 = (float*)d_out;                // [64,512] weighted output
  float* attn = out0 + 64 * 512;              // [64,2048] scores -> attn (in place)
  __half* Wws = (__half*)d_ws;                // 512 KB repacked W
  float* part = (float*)((char*)d_ws + 512 * 1024);  // 4 MB partials

  k0_cvt_w<<<128, 256, 0, stream>>>(W, Wws);
  k1_scores<<<2048, 256, 0, stream>>>(enc, msk, bias, ctx, Wws, attn);
  k2_softmax<<<64, 256, 0, stream>>>(attn);
  k3a_wsum<<<2048, 256, 0, stream>>>(enc, attn, part);
  k3b_reduce<<<128, 256, 0, stream>>>(part, out0);
}